// Round 2
// baseline (126.727 us; speedup 1.0000x reference)
//
#include <hip/hip_runtime.h>
#include <hip/hip_bf16.h>
#include <hip/hip_cooperative_groups.h>

namespace cg = cooperative_groups;

// out[b] = dot(user_factors[user_indices[b]], s),  s[f] = sum_c item_factors[item_indices[c], f]
// Single cooperative kernel: overlap item-row and user-row gathers, grid-sync, dot.

#define FDIM 64
#define NCOPY 16            // spread copies of s to dilute atomic contention
#define NBLOCKS 1024
#define NTHREADS 256
#define WPB (NTHREADS / 64) // waves per block = 4
#define PER_WAVE 4          // 16384 / (1024*4)

__global__ void __launch_bounds__(NTHREADS, 4)
mf_fused(const int* __restrict__ user_idx, const int* __restrict__ item_idx,
         const float* __restrict__ user_factors, const float* __restrict__ item_factors,
         float* __restrict__ out, float* __restrict__ s_part, int B) {
    const int lane  = threadIdx.x & 63;
    const int wid   = threadIdx.x >> 6;
    const int gwave = blockIdx.x * WPB + wid;
    const int nwaves = gridDim.x * WPB;

    // ---- issue all index loads first (items + users), then all row gathers ----
    int ib[PER_WAVE], iidx[PER_WAVE], uidx[PER_WAVE];
    #pragma unroll
    for (int k = 0; k < PER_WAVE; ++k) {
        ib[k]   = gwave + k * nwaves;
        iidx[k] = (ib[k] < B) ? item_idx[ib[k]] : 0;
        uidx[k] = (ib[k] < B) ? user_idx[ib[k]] : 0;
    }

    float acc = 0.0f;           // per-lane item-feature partial
    float urow[PER_WAVE];       // user rows held in regs (1 float/lane each)
    #pragma unroll
    for (int k = 0; k < PER_WAVE; ++k) {
        float r = (ib[k] < B) ? item_factors[(size_t)iidx[k] * FDIM + lane] : 0.0f;
        urow[k] = (ib[k] < B) ? user_factors[(size_t)uidx[k] * FDIM + lane] : 0.0f;
        acc += r;
    }

    // ---- block-level reduce of item partials, then atomic into spread copy ----
    __shared__ float red[NTHREADS];
    red[threadIdx.x] = acc;
    __syncthreads();
    if (threadIdx.x < FDIM) {
        float v = red[threadIdx.x] + red[threadIdx.x + 64] +
                  red[threadIdx.x + 128] + red[threadIdx.x + 192];
        atomicAdd(&s_part[(blockIdx.x & (NCOPY - 1)) * FDIM + threadIdx.x], v);
    }
    __threadfence();
    cg::this_grid().sync();

    // ---- s[lane] = sum of the NCOPY spread copies (L2-broadcast, cheap) ----
    float s = 0.0f;
    #pragma unroll
    for (int k = 0; k < NCOPY; ++k) s += s_part[k * FDIM + lane];

    // ---- per-output dot: lane f has u[f]*s[f]; 64-lane shuffle reduce ----
    #pragma unroll
    for (int k = 0; k < PER_WAVE; ++k) {
        float v = urow[k] * s;
        v += __shfl_down(v, 32);
        v += __shfl_down(v, 16);
        v += __shfl_down(v, 8);
        v += __shfl_down(v, 4);
        v += __shfl_down(v, 2);
        v += __shfl_down(v, 1);
        if (lane == 0 && ib[k] < B) out[ib[k]] = v;
    }
}

extern "C" void kernel_launch(void* const* d_in, const int* in_sizes, int n_in,
                              void* d_out, int out_size, void* d_ws, size_t ws_size,
                              hipStream_t stream) {
    const int*   user_idx     = (const int*)d_in[0];
    const int*   item_idx     = (const int*)d_in[1];
    const float* user_factors = (const float*)d_in[2];
    const float* item_factors = (const float*)d_in[3];
    float*       out          = (float*)d_out;
    float*       s_part       = (float*)d_ws;   // NCOPY*FDIM floats
    int B = in_sizes[0];

    hipMemsetAsync(d_ws, 0, NCOPY * FDIM * sizeof(float), stream);

    void* args[] = {(void*)&user_idx, (void*)&item_idx, (void*)&user_factors,
                    (void*)&item_factors, (void*)&out, (void*)&s_part, (void*)&B};
    hipLaunchCooperativeKernel((const void*)mf_fused, dim3(NBLOCKS), dim3(NTHREADS),
                               args, 0, stream);
}

// Round 3
// 17.485 us; speedup vs baseline: 7.2477x; 7.2477x over previous
//
#include <hip/hip_runtime.h>
#include <hip/hip_bf16.h>

// out[b] = dot(user_factors[user_indices[b]], s)
// s[f]   = sum_c item_factors[item_indices[c], f],  F = 64
//
// 3 graph nodes: memset(s_part) -> item_sum(1024 blocks, spread atomics)
//                -> user_dot(4096 blocks).

#define FDIM 64
#define NCOPY 16
#define NB_ITEM 1024
#define NTHREADS 256
#define WPB (NTHREADS / 64)   // 4 waves/block

__global__ void __launch_bounds__(NTHREADS, 4)
mf_item_sum(const int* __restrict__ item_idx,
            const float* __restrict__ item_factors,
            float* __restrict__ s_part, int B) {
    const int lane  = threadIdx.x & 63;
    const int gwave = blockIdx.x * WPB + (threadIdx.x >> 6);
    const int nwaves = gridDim.x * WPB;   // 4096
    const int per_wave = (B + nwaves - 1) / nwaves;  // 4

    // Preload indices so the row gathers are independent (all in flight).
    int rows[8];
    #pragma unroll
    for (int k = 0; k < 4; ++k) {
        int i = gwave + k * nwaves;
        rows[k] = (k < per_wave && i < B) ? item_idx[i] : -1;
    }

    float acc = 0.0f;
    #pragma unroll
    for (int k = 0; k < 4; ++k) {
        if (rows[k] >= 0)
            acc += item_factors[(size_t)rows[k] * FDIM + lane];
    }

    __shared__ float red[NTHREADS];
    red[threadIdx.x] = acc;
    __syncthreads();
    if (threadIdx.x < FDIM) {
        float v = red[threadIdx.x] + red[threadIdx.x + 64] +
                  red[threadIdx.x + 128] + red[threadIdx.x + 192];
        atomicAdd(&s_part[(blockIdx.x & (NCOPY - 1)) * FDIM + threadIdx.x], v);
    }
}

__global__ void __launch_bounds__(NTHREADS, 4)
mf_user_dot(const int* __restrict__ user_idx,
            const float* __restrict__ user_factors,
            const float* __restrict__ s_part,
            float* __restrict__ out, int B) {
    const int lane = threadIdx.x & 63;
    const int b = blockIdx.x * WPB + (threadIdx.x >> 6);
    if (b >= B) return;

    // s[lane] = sum of the 16 spread copies (L2-resident broadcast).
    float s = 0.0f;
    #pragma unroll
    for (int k = 0; k < NCOPY; ++k) s += s_part[k * FDIM + lane];

    const int idx = user_idx[b];
    float v = user_factors[(size_t)idx * FDIM + lane] * s;
    v += __shfl_down(v, 32);
    v += __shfl_down(v, 16);
    v += __shfl_down(v, 8);
    v += __shfl_down(v, 4);
    v += __shfl_down(v, 2);
    v += __shfl_down(v, 1);
    if (lane == 0) out[b] = v;
}

extern "C" void kernel_launch(void* const* d_in, const int* in_sizes, int n_in,
                              void* d_out, int out_size, void* d_ws, size_t ws_size,
                              hipStream_t stream) {
    const int*   user_idx     = (const int*)d_in[0];
    const int*   item_idx     = (const int*)d_in[1];
    const float* user_factors = (const float*)d_in[2];
    const float* item_factors = (const float*)d_in[3];
    float*       out          = (float*)d_out;
    float*       s_part       = (float*)d_ws;   // NCOPY * FDIM floats
    const int B = in_sizes[0];

    hipMemsetAsync(d_ws, 0, NCOPY * FDIM * sizeof(float), stream);
    mf_item_sum<<<NB_ITEM, NTHREADS, 0, stream>>>(item_idx, item_factors, s_part, B);
    const int nb_dot = (B + WPB - 1) / WPB;  // 4096
    mf_user_dot<<<nb_dot, NTHREADS, 0, stream>>>(user_idx, user_factors, s_part, out, B);
}